// Round 12
// baseline (167.785 us; speedup 1.0000x reference)
//
#include <hip/hip_runtime.h>
#include <math.h>

// Problem constants
#define B64 64
#define IN_SH 10000
#define EXP_SH 53
#define HID 1500
#define NPAD1 1536          // padded N for gemm1 accumulator
#define NBC 2048
#define K2 1553
#define KS1 40              // split-K chunks gemm1 (24*40 = 960 blocks)
#define KST1 8              // 8 steps of 32 => kchunk 256
#define KS2 13              // 32*13 = 416 blocks
#define KST2 4              // 4 steps of 32 => kchunk 128
#define CMCH 32             // colmax row chunks
#define WLDS 640            // dwords per wave LDS buffer (32 rows * 20)

using short8  = __attribute__((ext_vector_type(8))) short;
using floatx4 = __attribute__((ext_vector_type(4))) float;
using uintx4  = __attribute__((ext_vector_type(4))) unsigned int;

__device__ __forceinline__ unsigned short f2bf(float f) {
    unsigned u = __float_as_uint(f);
    u += 0x7fffu + ((u >> 16) & 1u);   // RNE
    return (unsigned short)(u >> 16);
}

// B-fragment order (per 32-k step):
//   frag[(step*4 + sgrp)*64 + lane][j] = act[b = sgrp*16 + (lane&15)][k = step*32 + (lane>>4)*8 + j]

// Node 1: [0,320) build gosBf; [320,576) hpo partial column max; [576,584) zero accumulators.
__global__ __launch_bounds__(256) void prep_k(const float* __restrict__ g,
                                              unsigned short* __restrict__ gosBf,
                                              const float* __restrict__ M,
                                              float* __restrict__ cm,
                                              float* __restrict__ accz) {
    int bi = blockIdx.x;
    if (bi < 320) {
        int t    = bi * 256 + threadIdx.x;   // [0, 81920)
        int lane = t & 63;
        int sgrp = (t >> 6) & 3;
        int step = t >> 8;                   // [0, 320)
        int q    = lane >> 4;
        int l15  = lane & 15;
        int b    = sgrp * 16 + l15;
        int k0   = step * 32 + q * 8;
        const float* p = g + (size_t)b * IN_SH + k0;
        unsigned int o[4];
        #pragma unroll
        for (int i = 0; i < 4; i++) {
            float lo = (k0 + 2 * i     < IN_SH) ? p[2 * i]     : 0.f;
            float hi = (k0 + 2 * i + 1 < IN_SH) ? p[2 * i + 1] : 0.f;
            o[i] = (unsigned)f2bf(lo) | ((unsigned)f2bf(hi) << 16);
        }
        uintx4 v; v.x = o[0]; v.y = o[1]; v.z = o[2]; v.w = o[3];
        *(uintx4*)(gosBf + (size_t)t * 8) = v;
    } else if (bi < 576) {
        int ci = bi - 320;                    // 256 blocks: 8 j-tiles x 32 row-chunks
        int j  = (ci & 7) * 256 + threadIdx.x;
        int i0 = (ci >> 3) * 64;
        float m = 0.0f;
        #pragma unroll 16
        for (int i = i0; i < i0 + 64; i++)
            m = fmaxf(m, M[(size_t)i * NBC + j]);
        cm[(ci >> 3) * NBC + j] = m;
    } else {
        // zero 229376 floats (hpre + logits contiguous): 8 blocks * 256 thr * 28 float4
        int t = (bi - 576) * 256 + threadIdx.x;
        floatx4 z = (floatx4){0.f, 0.f, 0.f, 0.f};
        #pragma unroll
        for (int i = 0; i < 28; i++)
            *(floatx4*)(accz + (size_t)(i * 2048 + t) * 4) = z;
    }
}

__device__ __forceinline__ void load_b4(const unsigned short* __restrict__ bf,
                                        int stg, uintx4 bv[4]) {
    #pragma unroll
    for (int s = 0; s < 4; s++)
        bv[s] = *(const uintx4*)(bf + (size_t)(stg * 4 + s) * 512);
}

// Barrier-free MFMA GEMM core (r11, best measured). Each wave stages its own
// 16-column W sub-tile into a wave-private LDS double buffer (intra-wave DS
// ops are in-order -> no __syncthreads in the K-loop; compiler emits
// fine-grained vmcnt/lgkmcnt). B-fragments come from `Bfc` (this k-chunk's
// fragment buffer: global for gemm1, LDS for fused gemm2).
// fp32 atomicAdd accumulation into accbuf[n*64+b].
template<int KSTEPS>
__device__ __forceinline__ void gemm_core(
    const float* __restrict__ W, const unsigned short* __restrict__ Bfc,
    float* __restrict__ accbuf, int N, int K, int ldw, int bx, int by, int tid,
    float* __restrict__ ldsw)   // this wave's 2*WLDS-dword region
{
    int lane = tid & 63;
    int q    = lane >> 4;
    int l15  = lane & 15;
    int n0   = bx * 64 + 16 * (tid >> 6);   // this wave's 16 columns
    int k0   = by * (KSTEPS * 32);
    bool fast = (n0 + 16 <= N) && (k0 + KSTEPS * 32 <= K);
    int kl  = lane >> 2;                    // 0..15  (staging row)
    int c4  = (lane & 3) * 4;               // staging col offset

    const unsigned short* bf = Bfc + (size_t)lane * 8;

    floatx4 acc[4];
    #pragma unroll
    for (int s = 0; s < 4; s++) acc[s] = (floatx4){0.f, 0.f, 0.f, 0.f};

    floatx4 g[2][2];   // [stage parity][row half]

    #define GLB(st, slot)                                                        \
        {                                                                        \
            int kb_ = k0 + (st) * 32;                                            \
            _Pragma("unroll")                                                    \
            for (int i_ = 0; i_ < 2; i_++) {                                     \
                int kg_ = kb_ + kl + 16 * i_;                                    \
                if (fast) {                                                      \
                    g[slot][i_] = *(const floatx4*)(W + (size_t)kg_ * ldw + n0 + c4); \
                } else {                                                         \
                    _Pragma("unroll")                                            \
                    for (int j_ = 0; j_ < 4; j_++)                               \
                        g[slot][i_][j_] = (kg_ < K && n0 + c4 + j_ < N)          \
                            ? W[(size_t)kg_ * ldw + n0 + c4 + j_] : 0.f;         \
                }                                                                \
            }                                                                    \
        }
    #define LWR(buf, slot)                                                       \
        {                                                                        \
            _Pragma("unroll")                                                    \
            for (int i_ = 0; i_ < 2; i_++)                                       \
                *(floatx4*)(ldsw + (buf) * WLDS + (kl + 16 * i_) * 20 + c4) = g[slot][i_]; \
        }

    GLB(0, 0);
    if (KSTEPS > 1) GLB(1, 1);
    LWR(0, 0);

    uintx4 bv[2][4];
    load_b4(bf, 0, bv[0]);
    if (KSTEPS > 1) load_b4(bf, 1, bv[1]);

    #pragma unroll
    for (int st = 0; st < KSTEPS; st++) {
        const int s = st & 1;                     // compile-time after unroll
        const float* lb = ldsw + s * WLDS;

        short8 af;
        #pragma unroll
        for (int j = 0; j < 8; j++)
            af[j] = (short)f2bf(lb[(q * 8 + j) * 20 + l15]);

        uintx4 bt[4];
        if (st + 2 < KSTEPS) {
            GLB(st + 2, s);
            load_b4(bf, st + 2, bt);
        }

        #pragma unroll
        for (int m = 0; m < 4; m++) {
            short8 bf8 = __builtin_bit_cast(short8, bv[s][m]);
            acc[m] = __builtin_amdgcn_mfma_f32_16x16x32_bf16(af, bf8, acc[m], 0, 0, 0);
        }

        if (st + 1 < KSTEPS) LWR(1 - s, 1 - s);
        if (st + 2 < KSTEPS) {
            #pragma unroll
            for (int m = 0; m < 4; m++) bv[s][m] = bt[m];
        }
    }
    #undef GLB
    #undef LWR

    // D lane mapping: col=lane&15 (batch within group s), row=q*4+r (n offset)
    int nrow = n0 + q * 4;
    #pragma unroll
    for (int s = 0; s < 4; s++) {
        #pragma unroll
        for (int rr = 0; rr < 4; rr++)
            atomicAdd(&accbuf[(size_t)(nrow + rr) * 64 + s * 16 + l15], acc[s][rr]);
    }
}

// Node 2: GEMM1  h_pre += gos @ W1  (N=1500, K=10000)
__global__ __launch_bounds__(256) void gemm1_k(
    const float* __restrict__ W1, const unsigned short* __restrict__ gosBf,
    float* __restrict__ hpre)
{
    __shared__ float lds[4 * 2 * WLDS];
    gemm_core<KST1>(W1, gosBf + (size_t)blockIdx.y * (KST1 * 4) * 512,
                    hpre, HID, IN_SH, HID, blockIdx.x, blockIdx.y,
                    threadIdx.x, lds + (threadIdx.x >> 6) * (2 * WLDS));
}

// Node 3: fused combine + GEMM2.
// Phase A: build this k-chunk's B-fragments in LDS from hpre (bias + exact
// GELU) / exp_x concat / zero pad — hpre visibility guaranteed by the
// gemm1 kernel boundary. Phase B: gemm core, B-fragments from LDS.
__global__ __launch_bounds__(256) void gemm2_k(
    const float* __restrict__ W2, const float* __restrict__ hpre,
    const float* __restrict__ b1, const float* __restrict__ expx,
    float* __restrict__ logits)
{
    __shared__ float lds[4 * 2 * WLDS];
    __shared__ unsigned short bfrag[KST2 * 4 * 64 * 8];   // 16 KB
    int tid = threadIdx.x;
    int by  = blockIdx.y;

    // Phase A: 1024 tuples of 8, 4 per thread
    #pragma unroll
    for (int it = 0; it < 4; it++) {
        int tl   = it * 256 + tid;          // [0, 1024)
        int stg  = tl >> 8;                 // 0..3
        int sgrp = (tl >> 6) & 3;
        int lane = tl & 63;
        int b    = sgrp * 16 + (lane & 15);
        int nb   = (by * 4 + stg) * 32 + (lane >> 4) * 8;
        unsigned int o[4];
        #pragma unroll
        for (int i = 0; i < 4; i++) {
            unsigned int lohi[2];
            #pragma unroll
            for (int h = 0; h < 2; h++) {
                int n = nb + 2 * i + h;
                float v = 0.f;
                if (n < HID) {
                    float s = hpre[(size_t)n * 64 + b] + b1[n];
                    v = 0.5f * s * (1.0f + erff(s * 0.70710678118654752f));
                } else if (n < HID + EXP_SH) {
                    v = expx[b * EXP_SH + (n - HID)];
                }
                lohi[h] = f2bf(v);
            }
            o[i] = lohi[0] | (lohi[1] << 16);
        }
        uintx4 v; v.x = o[0]; v.y = o[1]; v.z = o[2]; v.w = o[3];
        *(uintx4*)(bfrag + (size_t)tl * 8) = v;
    }
    __syncthreads();

    // Phase B
    gemm_core<KST2>(W2, bfrag, logits, NBC, K2, NBC, blockIdx.x, by,
                    tid, lds + (tid >> 6) * (2 * WLDS));
}

// Node 4: bias + sigmoid on logits, multiply by column max (reduce 32 chunks)
__global__ __launch_bounds__(256) void final_k(
    const float* __restrict__ logits, const float* __restrict__ b2,
    const float* __restrict__ cm, float* __restrict__ out)
{
    int idx = blockIdx.x * 256 + threadIdx.x;   // 64*2048 threads
    int b = idx & 63;
    int j = idx >> 6;
    float s = logits[(size_t)j * 64 + b] + b2[j];
    float sig = 1.0f / (1.0f + expf(-s));
    float m = 0.f;
    #pragma unroll
    for (int c = 0; c < CMCH; c++) m = fmaxf(m, cm[c * NBC + j]);
    out[(size_t)b * NBC + j] = sig * m;
}

extern "C" void kernel_launch(void* const* d_in, const int* in_sizes, int n_in,
                              void* d_out, int out_size, void* d_ws, size_t ws_size,
                              hipStream_t stream) {
    const float* gos  = (const float*)d_in[0];
    const float* expx = (const float*)d_in[1];
    const float* W1   = (const float*)d_in[2];
    const float* b1   = (const float*)d_in[3];
    const float* W2   = (const float*)d_in[4];
    const float* b2   = (const float*)d_in[5];
    const float* hpo  = (const float*)d_in[6];
    float* out = (float*)d_out;

    // workspace layout (16B-aligned offsets)
    char* ws = (char*)d_ws;
    unsigned short* gosBf = (unsigned short*)ws;                   // 320*4*64*8*2 = 1,310,720
    float* hpre   = (float*)(ws + 1310720);                        // 1536*64*4    =   393,216
    float* logits = (float*)(ws + 1310720 + 393216);               // 2048*64*4    =   524,288 (contiguous with hpre)
    float* cm     = (float*)(ws + 1310720 + 393216 + 524288);      // 32*2048*4    =   262,144
    // total ~2.5 MB

    // 1) build gosBf | hpo partial column-max | zero accumulators
    prep_k<<<584, 256, 0, stream>>>(gos, gosBf, hpo, cm, hpre);

    // 2) GEMM1 (atomic split-K, barrier-free wave-private LDS staging)
    gemm1_k<<<dim3(NPAD1 / 64, KS1), 256, 0, stream>>>(W1, gosBf, hpre);

    // 3) fused combine (bias+GELU+concat, per-block LDS fragments) + GEMM2
    gemm2_k<<<dim3(NBC / 64, KS2), 256, 0, stream>>>(W2, hpre, b1, expx, logits);

    // 4) bias + sigmoid + *colmax -> out
    final_k<<<(B64 * NBC) / 256, 256, 0, stream>>>(logits, b2, cm, out);
}

// Round 13
// 161.011 us; speedup vs baseline: 1.0421x; 1.0421x over previous
//
#include <hip/hip_runtime.h>
#include <math.h>

// Problem constants
#define B64 64
#define IN_SH 10000
#define EXP_SH 53
#define HID 1500
#define NPAD1 1536          // padded N for gemm1 accumulator
#define NBC 2048
#define K2 1553
#define KS1 20              // split-K chunks gemm1 (24*20 = 480 blocks) — halves atomics vs 40
#define KST1 16             // 16 steps of 32 => kchunk 512 (20*512 = 10240 = padded K)
#define KS2 13              // 32*13 = 416 blocks
#define KST2 4              // 4 steps of 32 => kchunk 128
#define CMCH 32             // colmax row chunks
#define WLDS 640            // dwords per wave LDS buffer (32 rows * 20)

using short8  = __attribute__((ext_vector_type(8))) short;
using floatx4 = __attribute__((ext_vector_type(4))) float;
using uintx4  = __attribute__((ext_vector_type(4))) unsigned int;

__device__ __forceinline__ unsigned short f2bf(float f) {
    unsigned u = __float_as_uint(f);
    u += 0x7fffu + ((u >> 16) & 1u);   // RNE
    return (unsigned short)(u >> 16);
}

// B-fragment order (per 32-k step):
//   frag[(step*4 + sgrp)*64 + lane][j] = act[b = sgrp*16 + (lane&15)][k = step*32 + (lane>>4)*8 + j]

// Node 1: [0,320) build gosBf; [320,576) hpo partial column max; [576,584) zero accumulators.
__global__ __launch_bounds__(256) void prep_k(const float* __restrict__ g,
                                              unsigned short* __restrict__ gosBf,
                                              const float* __restrict__ M,
                                              float* __restrict__ cm,
                                              float* __restrict__ accz) {
    int bi = blockIdx.x;
    if (bi < 320) {
        int t    = bi * 256 + threadIdx.x;   // [0, 81920)
        int lane = t & 63;
        int sgrp = (t >> 6) & 3;
        int step = t >> 8;                   // [0, 320)
        int q    = lane >> 4;
        int l15  = lane & 15;
        int b    = sgrp * 16 + l15;
        int k0   = step * 32 + q * 8;
        const float* p = g + (size_t)b * IN_SH + k0;
        unsigned int o[4];
        #pragma unroll
        for (int i = 0; i < 4; i++) {
            float lo = (k0 + 2 * i     < IN_SH) ? p[2 * i]     : 0.f;
            float hi = (k0 + 2 * i + 1 < IN_SH) ? p[2 * i + 1] : 0.f;
            o[i] = (unsigned)f2bf(lo) | ((unsigned)f2bf(hi) << 16);
        }
        uintx4 v; v.x = o[0]; v.y = o[1]; v.z = o[2]; v.w = o[3];
        *(uintx4*)(gosBf + (size_t)t * 8) = v;
    } else if (bi < 576) {
        int ci = bi - 320;                    // 256 blocks: 8 j-tiles x 32 row-chunks
        int j  = (ci & 7) * 256 + threadIdx.x;
        int i0 = (ci >> 3) * 64;
        float m = 0.0f;
        #pragma unroll 16
        for (int i = i0; i < i0 + 64; i++)
            m = fmaxf(m, M[(size_t)i * NBC + j]);
        cm[(ci >> 3) * NBC + j] = m;
    } else {
        // zero 229376 floats (hpre + logits contiguous): 8 blocks * 256 thr * 28 float4
        int t = (bi - 576) * 256 + threadIdx.x;
        floatx4 z = (floatx4){0.f, 0.f, 0.f, 0.f};
        #pragma unroll
        for (int i = 0; i < 28; i++)
            *(floatx4*)(accz + (size_t)(i * 2048 + t) * 4) = z;
    }
}

__device__ __forceinline__ void load_b4(const unsigned short* __restrict__ bf,
                                        int stg, uintx4 bv[4]) {
    #pragma unroll
    for (int s = 0; s < 4; s++)
        bv[s] = *(const uintx4*)(bf + (size_t)(stg * 4 + s) * 512);
}

// Barrier-free MFMA GEMM core (r11). Each wave stages its own 16-column W
// sub-tile into a wave-private LDS double buffer (intra-wave DS ops are
// in-order -> no __syncthreads in the K-loop; compiler emits fine-grained
// vmcnt/lgkmcnt). fp32 atomicAdd accumulation into accbuf[n*64+b].
template<int KSTEPS>
__device__ __forceinline__ void gemm_core(
    const float* __restrict__ W, const unsigned short* __restrict__ Bfc,
    float* __restrict__ accbuf, int N, int K, int ldw, int bx, int by, int tid,
    float* __restrict__ ldsw)   // this wave's 2*WLDS-dword region
{
    int lane = tid & 63;
    int q    = lane >> 4;
    int l15  = lane & 15;
    int n0   = bx * 64 + 16 * (tid >> 6);   // this wave's 16 columns
    int k0   = by * (KSTEPS * 32);
    bool fast = (n0 + 16 <= N) && (k0 + KSTEPS * 32 <= K);
    int kl  = lane >> 2;                    // 0..15  (staging row)
    int c4  = (lane & 3) * 4;               // staging col offset

    const unsigned short* bf = Bfc + (size_t)lane * 8;

    floatx4 acc[4];
    #pragma unroll
    for (int s = 0; s < 4; s++) acc[s] = (floatx4){0.f, 0.f, 0.f, 0.f};

    floatx4 g[2][2];   // [stage parity][row half]

    #define GLB(st, slot)                                                        \
        {                                                                        \
            int kb_ = k0 + (st) * 32;                                            \
            _Pragma("unroll")                                                    \
            for (int i_ = 0; i_ < 2; i_++) {                                     \
                int kg_ = kb_ + kl + 16 * i_;                                    \
                if (fast) {                                                      \
                    g[slot][i_] = *(const floatx4*)(W + (size_t)kg_ * ldw + n0 + c4); \
                } else {                                                         \
                    _Pragma("unroll")                                            \
                    for (int j_ = 0; j_ < 4; j_++)                               \
                        g[slot][i_][j_] = (kg_ < K && n0 + c4 + j_ < N)          \
                            ? W[(size_t)kg_ * ldw + n0 + c4 + j_] : 0.f;         \
                }                                                                \
            }                                                                    \
        }
    #define LWR(buf, slot)                                                       \
        {                                                                        \
            _Pragma("unroll")                                                    \
            for (int i_ = 0; i_ < 2; i_++)                                       \
                *(floatx4*)(ldsw + (buf) * WLDS + (kl + 16 * i_) * 20 + c4) = g[slot][i_]; \
        }

    GLB(0, 0);
    if (KSTEPS > 1) GLB(1, 1);
    LWR(0, 0);

    uintx4 bv[2][4];
    load_b4(bf, 0, bv[0]);
    if (KSTEPS > 1) load_b4(bf, 1, bv[1]);

    #pragma unroll
    for (int st = 0; st < KSTEPS; st++) {
        const int s = st & 1;                     // compile-time after unroll
        const float* lb = ldsw + s * WLDS;

        short8 af;
        #pragma unroll
        for (int j = 0; j < 8; j++)
            af[j] = (short)f2bf(lb[(q * 8 + j) * 20 + l15]);

        uintx4 bt[4];
        if (st + 2 < KSTEPS) {
            GLB(st + 2, s);
            load_b4(bf, st + 2, bt);
        }

        #pragma unroll
        for (int m = 0; m < 4; m++) {
            short8 bf8 = __builtin_bit_cast(short8, bv[s][m]);
            acc[m] = __builtin_amdgcn_mfma_f32_16x16x32_bf16(af, bf8, acc[m], 0, 0, 0);
        }

        if (st + 1 < KSTEPS) LWR(1 - s, 1 - s);
        if (st + 2 < KSTEPS) {
            #pragma unroll
            for (int m = 0; m < 4; m++) bv[s][m] = bt[m];
        }
    }
    #undef GLB
    #undef LWR

    // D lane mapping: col=lane&15 (batch within group s), row=q*4+r (n offset)
    int nrow = n0 + q * 4;
    #pragma unroll
    for (int s = 0; s < 4; s++) {
        #pragma unroll
        for (int rr = 0; rr < 4; rr++)
            atomicAdd(&accbuf[(size_t)(nrow + rr) * 64 + s * 16 + l15], acc[s][rr]);
    }
}

// Node 2: GEMM1  h_pre += gos @ W1  (N=1500, K=10000)
__global__ __launch_bounds__(256) void gemm1_k(
    const float* __restrict__ W1, const unsigned short* __restrict__ gosBf,
    float* __restrict__ hpre)
{
    __shared__ float lds[4 * 2 * WLDS];
    gemm_core<KST1>(W1, gosBf + (size_t)blockIdx.y * (KST1 * 4) * 512,
                    hpre, HID, IN_SH, HID, blockIdx.x, blockIdx.y,
                    threadIdx.x, lds + (threadIdx.x >> 6) * (2 * WLDS));
}

// Node 4: GEMM2  logits += X @ W2  (N=2048, K=1553)
__global__ __launch_bounds__(256) void gemm2_k(
    const float* __restrict__ W2, const unsigned short* __restrict__ Xf,
    float* __restrict__ logits)
{
    __shared__ float lds[4 * 2 * WLDS];
    gemm_core<KST2>(W2, Xf + (size_t)blockIdx.y * (KST2 * 4) * 512,
                    logits, NBC, K2, NBC, blockIdx.x, blockIdx.y,
                    threadIdx.x, lds + (threadIdx.x >> 6) * (2 * WLDS));
}

// Node 3: bias + exact GELU on h_pre, concat exp_x, emit Xf in B-fragment order.
__global__ __launch_bounds__(256) void combine1(
    const float* __restrict__ hpre, const float* __restrict__ b1,
    const float* __restrict__ expx, unsigned short* __restrict__ Xf)
{
    int t    = blockIdx.x * 256 + threadIdx.x;   // [0, 13312)
    int lane = t & 63;
    int sgrp = (t >> 6) & 3;
    int step = t >> 8;                            // [0, 52)
    int q    = lane >> 4;
    int l15  = lane & 15;
    int b    = sgrp * 16 + l15;
    int kb   = step * 32 + q * 8;
    unsigned int o[4];
    #pragma unroll
    for (int i = 0; i < 4; i++) {
        unsigned int lohi[2];
        #pragma unroll
        for (int h = 0; h < 2; h++) {
            int n = kb + 2 * i + h;
            float v = 0.f;
            if (n < HID) {
                float s = hpre[(size_t)n * 64 + b] + b1[n];
                v = 0.5f * s * (1.0f + erff(s * 0.70710678118654752f));
            } else if (n < HID + EXP_SH) {
                v = expx[b * EXP_SH + (n - HID)];
            }
            lohi[h] = f2bf(v);
        }
        o[i] = lohi[0] | (lohi[1] << 16);
    }
    uintx4 v; v.x = o[0]; v.y = o[1]; v.z = o[2]; v.w = o[3];
    *(uintx4*)(Xf + (size_t)t * 8) = v;
}

// Node 5: bias + sigmoid on logits, multiply by column max (reduce 32 chunks)
__global__ __launch_bounds__(256) void final_k(
    const float* __restrict__ logits, const float* __restrict__ b2,
    const float* __restrict__ cm, float* __restrict__ out)
{
    int idx = blockIdx.x * 256 + threadIdx.x;   // 64*2048 threads
    int b = idx & 63;
    int j = idx >> 6;
    float s = logits[(size_t)j * 64 + b] + b2[j];
    float sig = 1.0f / (1.0f + expf(-s));
    float m = 0.f;
    #pragma unroll
    for (int c = 0; c < CMCH; c++) m = fmaxf(m, cm[c * NBC + j]);
    out[(size_t)b * NBC + j] = sig * m;
}

extern "C" void kernel_launch(void* const* d_in, const int* in_sizes, int n_in,
                              void* d_out, int out_size, void* d_ws, size_t ws_size,
                              hipStream_t stream) {
    const float* gos  = (const float*)d_in[0];
    const float* expx = (const float*)d_in[1];
    const float* W1   = (const float*)d_in[2];
    const float* b1   = (const float*)d_in[3];
    const float* W2   = (const float*)d_in[4];
    const float* b2   = (const float*)d_in[5];
    const float* hpo  = (const float*)d_in[6];
    float* out = (float*)d_out;

    // workspace layout (16B-aligned offsets)
    char* ws = (char*)d_ws;
    unsigned short* gosBf = (unsigned short*)ws;                   // 320*4*64*8*2 = 1,310,720
    float* hpre   = (float*)(ws + 1310720);                        // 1536*64*4    =   393,216
    float* logits = (float*)(ws + 1310720 + 393216);               // 2048*64*4    =   524,288 (contiguous with hpre)
    unsigned short* Xf = (unsigned short*)(ws + 1310720 + 393216 + 524288);  // 52*4*64*8*2 = 212,992
    float* cm = (float*)(ws + 1310720 + 393216 + 524288 + 212992); // 32*2048*4    =   262,144
    // total ~2.7 MB

    // 1) build gosBf | hpo partial column-max | zero accumulators
    prep_k<<<584, 256, 0, stream>>>(gos, gosBf, hpo, cm, hpre);

    // 2) GEMM1 (atomic split-K, KS1=20: half the atomics of r11)
    gemm1_k<<<dim3(NPAD1 / 64, KS1), 256, 0, stream>>>(W1, gosBf, hpre);

    // 3) bias + gelu + concat exp_x -> Xf (B-fragment order)
    combine1<<<52, 256, 0, stream>>>(hpre, b1, expx, Xf);

    // 4) GEMM2 (atomic split-K, barrier-free wave-private LDS staging)
    gemm2_k<<<dim3(NBC / 64, KS2), 256, 0, stream>>>(W2, Xf, logits);

    // 5) bias + sigmoid + *colmax -> out
    final_k<<<(B64 * NBC) / 256, 256, 0, stream>>>(logits, b2, cm, out);
}

// Round 14
// 158.410 us; speedup vs baseline: 1.0592x; 1.0164x over previous
//
#include <hip/hip_runtime.h>
#include <math.h>

// Problem constants
#define B64 64
#define IN_SH 10000
#define EXP_SH 53
#define HID 1500
#define NPAD1 1536          // padded N for gemm1 accumulator
#define NBC 2048
#define K2 1553
#define KS1 20              // split-K chunks gemm1 (24*20 = 480 blocks)
#define KST1 16             // 16 steps of 32 => kchunk 512 (20*512 = 10240 = padded K)
#define KS2 7               // 32*7 = 224 blocks — halves gemm2 atomics vs 13
#define KST2 8              // 8 steps of 32 => kchunk 256 (7*256 = 1792 = padded K2)
#define XSTEP 56            // Xf k-steps (1792/32), zero-padded past 1553
#define CMCH 32             // colmax row chunks
#define WLDS 640            // dwords per wave LDS buffer (32 rows * 20)

using short8  = __attribute__((ext_vector_type(8))) short;
using floatx4 = __attribute__((ext_vector_type(4))) float;
using uintx4  = __attribute__((ext_vector_type(4))) unsigned int;

__device__ __forceinline__ unsigned short f2bf(float f) {
    unsigned u = __float_as_uint(f);
    u += 0x7fffu + ((u >> 16) & 1u);   // RNE
    return (unsigned short)(u >> 16);
}

// B-fragment order (per 32-k step):
//   frag[(step*4 + sgrp)*64 + lane][j] = act[b = sgrp*16 + (lane&15)][k = step*32 + (lane>>4)*8 + j]

// Node 1: [0,320) build gosBf; [320,576) hpo partial column max; [576,584) zero accumulators.
__global__ __launch_bounds__(256) void prep_k(const float* __restrict__ g,
                                              unsigned short* __restrict__ gosBf,
                                              const float* __restrict__ M,
                                              float* __restrict__ cm,
                                              float* __restrict__ accz) {
    int bi = blockIdx.x;
    if (bi < 320) {
        int t    = bi * 256 + threadIdx.x;   // [0, 81920)
        int lane = t & 63;
        int sgrp = (t >> 6) & 3;
        int step = t >> 8;                   // [0, 320)
        int q    = lane >> 4;
        int l15  = lane & 15;
        int b    = sgrp * 16 + l15;
        int k0   = step * 32 + q * 8;
        const float* p = g + (size_t)b * IN_SH + k0;
        unsigned int o[4];
        #pragma unroll
        for (int i = 0; i < 4; i++) {
            float lo = (k0 + 2 * i     < IN_SH) ? p[2 * i]     : 0.f;
            float hi = (k0 + 2 * i + 1 < IN_SH) ? p[2 * i + 1] : 0.f;
            o[i] = (unsigned)f2bf(lo) | ((unsigned)f2bf(hi) << 16);
        }
        uintx4 v; v.x = o[0]; v.y = o[1]; v.z = o[2]; v.w = o[3];
        *(uintx4*)(gosBf + (size_t)t * 8) = v;
    } else if (bi < 576) {
        int ci = bi - 320;                    // 256 blocks: 8 j-tiles x 32 row-chunks
        int j  = (ci & 7) * 256 + threadIdx.x;
        int i0 = (ci >> 3) * 64;
        float m = 0.0f;
        #pragma unroll 16
        for (int i = i0; i < i0 + 64; i++)
            m = fmaxf(m, M[(size_t)i * NBC + j]);
        cm[(ci >> 3) * NBC + j] = m;
    } else {
        // zero 229376 floats (hpre + logits contiguous): 8 blocks * 256 thr * 28 float4
        int t = (bi - 576) * 256 + threadIdx.x;
        floatx4 z = (floatx4){0.f, 0.f, 0.f, 0.f};
        #pragma unroll
        for (int i = 0; i < 28; i++)
            *(floatx4*)(accz + (size_t)(i * 2048 + t) * 4) = z;
    }
}

__device__ __forceinline__ void load_b4(const unsigned short* __restrict__ bf,
                                        int stg, uintx4 bv[4]) {
    #pragma unroll
    for (int s = 0; s < 4; s++)
        bv[s] = *(const uintx4*)(bf + (size_t)(stg * 4 + s) * 512);
}

// Barrier-free MFMA GEMM core (r11/r13). Each wave stages its own 16-column W
// sub-tile into a wave-private LDS double buffer (intra-wave DS ops are
// in-order -> no __syncthreads in the K-loop; compiler emits fine-grained
// vmcnt/lgkmcnt). fp32 atomicAdd accumulation into accbuf[n*64+b].
template<int KSTEPS>
__device__ __forceinline__ void gemm_core(
    const float* __restrict__ W, const unsigned short* __restrict__ Bfc,
    float* __restrict__ accbuf, int N, int K, int ldw, int bx, int by, int tid,
    float* __restrict__ ldsw)   // this wave's 2*WLDS-dword region
{
    int lane = tid & 63;
    int q    = lane >> 4;
    int l15  = lane & 15;
    int n0   = bx * 64 + 16 * (tid >> 6);   // this wave's 16 columns
    int k0   = by * (KSTEPS * 32);
    bool fast = (n0 + 16 <= N) && (k0 + KSTEPS * 32 <= K);
    int kl  = lane >> 2;                    // 0..15  (staging row)
    int c4  = (lane & 3) * 4;               // staging col offset

    const unsigned short* bf = Bfc + (size_t)lane * 8;

    floatx4 acc[4];
    #pragma unroll
    for (int s = 0; s < 4; s++) acc[s] = (floatx4){0.f, 0.f, 0.f, 0.f};

    floatx4 g[2][2];   // [stage parity][row half]

    #define GLB(st, slot)                                                        \
        {                                                                        \
            int kb_ = k0 + (st) * 32;                                            \
            _Pragma("unroll")                                                    \
            for (int i_ = 0; i_ < 2; i_++) {                                     \
                int kg_ = kb_ + kl + 16 * i_;                                    \
                if (fast) {                                                      \
                    g[slot][i_] = *(const floatx4*)(W + (size_t)kg_ * ldw + n0 + c4); \
                } else {                                                         \
                    _Pragma("unroll")                                            \
                    for (int j_ = 0; j_ < 4; j_++)                               \
                        g[slot][i_][j_] = (kg_ < K && n0 + c4 + j_ < N)          \
                            ? W[(size_t)kg_ * ldw + n0 + c4 + j_] : 0.f;         \
                }                                                                \
            }                                                                    \
        }
    #define LWR(buf, slot)                                                       \
        {                                                                        \
            _Pragma("unroll")                                                    \
            for (int i_ = 0; i_ < 2; i_++)                                       \
                *(floatx4*)(ldsw + (buf) * WLDS + (kl + 16 * i_) * 20 + c4) = g[slot][i_]; \
        }

    GLB(0, 0);
    if (KSTEPS > 1) GLB(1, 1);
    LWR(0, 0);

    uintx4 bv[2][4];
    load_b4(bf, 0, bv[0]);
    if (KSTEPS > 1) load_b4(bf, 1, bv[1]);

    #pragma unroll
    for (int st = 0; st < KSTEPS; st++) {
        const int s = st & 1;                     // compile-time after unroll
        const float* lb = ldsw + s * WLDS;

        short8 af;
        #pragma unroll
        for (int j = 0; j < 8; j++)
            af[j] = (short)f2bf(lb[(q * 8 + j) * 20 + l15]);

        uintx4 bt[4];
        if (st + 2 < KSTEPS) {
            GLB(st + 2, s);
            load_b4(bf, st + 2, bt);
        }

        #pragma unroll
        for (int m = 0; m < 4; m++) {
            short8 bf8 = __builtin_bit_cast(short8, bv[s][m]);
            acc[m] = __builtin_amdgcn_mfma_f32_16x16x32_bf16(af, bf8, acc[m], 0, 0, 0);
        }

        if (st + 1 < KSTEPS) LWR(1 - s, 1 - s);
        if (st + 2 < KSTEPS) {
            #pragma unroll
            for (int m = 0; m < 4; m++) bv[s][m] = bt[m];
        }
    }
    #undef GLB
    #undef LWR

    // D lane mapping: col=lane&15 (batch within group s), row=q*4+r (n offset)
    int nrow = n0 + q * 4;
    #pragma unroll
    for (int s = 0; s < 4; s++) {
        #pragma unroll
        for (int rr = 0; rr < 4; rr++)
            atomicAdd(&accbuf[(size_t)(nrow + rr) * 64 + s * 16 + l15], acc[s][rr]);
    }
}

// Node 2: GEMM1  h_pre += gos @ W1  (N=1500, K=10000)
__global__ __launch_bounds__(256) void gemm1_k(
    const float* __restrict__ W1, const unsigned short* __restrict__ gosBf,
    float* __restrict__ hpre)
{
    __shared__ float lds[4 * 2 * WLDS];
    gemm_core<KST1>(W1, gosBf + (size_t)blockIdx.y * (KST1 * 4) * 512,
                    hpre, HID, IN_SH, HID, blockIdx.x, blockIdx.y,
                    threadIdx.x, lds + (threadIdx.x >> 6) * (2 * WLDS));
}

// Node 4: GEMM2  logits += X @ W2  (N=2048, K=1553; Xf zero-padded to 1792)
__global__ __launch_bounds__(256) void gemm2_k(
    const float* __restrict__ W2, const unsigned short* __restrict__ Xf,
    float* __restrict__ logits)
{
    __shared__ float lds[4 * 2 * WLDS];
    gemm_core<KST2>(W2, Xf + (size_t)blockIdx.y * (KST2 * 4) * 512,
                    logits, NBC, K2, NBC, blockIdx.x, blockIdx.y,
                    threadIdx.x, lds + (threadIdx.x >> 6) * (2 * WLDS));
}

// Node 3: [0,56) bias + exact GELU on h_pre, concat exp_x, emit Xf (B-fragment
// order, zero-padded to 1792); [56,64) reduce cm's 32 chunks -> cmr[2048].
__global__ __launch_bounds__(256) void combine1(
    const float* __restrict__ hpre, const float* __restrict__ b1,
    const float* __restrict__ expx, unsigned short* __restrict__ Xf,
    const float* __restrict__ cm, float* __restrict__ cmr)
{
    int bi = blockIdx.x;
    if (bi < XSTEP) {
        int t    = bi * 256 + threadIdx.x;   // [0, 14336)
        int lane = t & 63;
        int sgrp = (t >> 6) & 3;
        int step = t >> 8;                    // [0, 56)
        int q    = lane >> 4;
        int l15  = lane & 15;
        int b    = sgrp * 16 + l15;
        int kb   = step * 32 + q * 8;
        unsigned int o[4];
        #pragma unroll
        for (int i = 0; i < 4; i++) {
            unsigned int lohi[2];
            #pragma unroll
            for (int h = 0; h < 2; h++) {
                int n = kb + 2 * i + h;
                float v = 0.f;
                if (n < HID) {
                    float s = hpre[(size_t)n * 64 + b] + b1[n];
                    v = 0.5f * s * (1.0f + erff(s * 0.70710678118654752f));
                } else if (n < HID + EXP_SH) {
                    v = expx[b * EXP_SH + (n - HID)];
                }
                lohi[h] = f2bf(v);
            }
            o[i] = lohi[0] | (lohi[1] << 16);
        }
        uintx4 v; v.x = o[0]; v.y = o[1]; v.z = o[2]; v.w = o[3];
        *(uintx4*)(Xf + (size_t)t * 8) = v;
    } else {
        int j = (bi - XSTEP) * 256 + threadIdx.x;   // 0..2047
        float m = 0.f;
        #pragma unroll
        for (int c = 0; c < CMCH; c++) m = fmaxf(m, cm[c * NBC + j]);
        cmr[j] = m;
    }
}

// Node 5: bias + sigmoid on logits, multiply by pre-reduced column max
__global__ __launch_bounds__(256) void final_k(
    const float* __restrict__ logits, const float* __restrict__ b2,
    const float* __restrict__ cmr, float* __restrict__ out)
{
    int idx = blockIdx.x * 256 + threadIdx.x;   // 64*2048 threads
    int b = idx & 63;
    int j = idx >> 6;
    float s = logits[(size_t)j * 64 + b] + b2[j];
    float sig = 1.0f / (1.0f + expf(-s));
    out[(size_t)b * NBC + j] = sig * cmr[j];
}

extern "C" void kernel_launch(void* const* d_in, const int* in_sizes, int n_in,
                              void* d_out, int out_size, void* d_ws, size_t ws_size,
                              hipStream_t stream) {
    const float* gos  = (const float*)d_in[0];
    const float* expx = (const float*)d_in[1];
    const float* W1   = (const float*)d_in[2];
    const float* b1   = (const float*)d_in[3];
    const float* W2   = (const float*)d_in[4];
    const float* b2   = (const float*)d_in[5];
    const float* hpo  = (const float*)d_in[6];
    float* out = (float*)d_out;

    // workspace layout (16B-aligned offsets)
    char* ws = (char*)d_ws;
    unsigned short* gosBf = (unsigned short*)ws;                   // 320*4*64*8*2 = 1,310,720
    float* hpre   = (float*)(ws + 1310720);                        // 1536*64*4    =   393,216
    float* logits = (float*)(ws + 1310720 + 393216);               // 2048*64*4    =   524,288 (contiguous with hpre)
    unsigned short* Xf = (unsigned short*)(ws + 2228224);          // 56*4*64*8*2  =   229,376
    float* cm  = (float*)(ws + 2228224 + 229376);                  // 32*2048*4    =   262,144
    float* cmr = (float*)(ws + 2228224 + 229376 + 262144);         // 2048*4       =     8,192
    // total ~2.7 MB

    // 1) build gosBf | hpo partial column-max | zero accumulators
    prep_k<<<584, 256, 0, stream>>>(gos, gosBf, hpo, cm, hpre);

    // 2) GEMM1 (atomic split-K, KS1=20)
    gemm1_k<<<dim3(NPAD1 / 64, KS1), 256, 0, stream>>>(W1, gosBf, hpre);

    // 3) bias + gelu + concat exp_x -> Xf (56 steps) | reduce cm -> cmr
    combine1<<<XSTEP + 8, 256, 0, stream>>>(hpre, b1, expx, Xf, cm, cmr);

    // 4) GEMM2 (atomic split-K, KS2=7: half the atomics of r13)
    gemm2_k<<<dim3(NBC / 64, KS2), 256, 0, stream>>>(W2, Xf, logits);

    // 5) bias + sigmoid + *cmr -> out
    final_k<<<(B64 * NBC) / 256, 256, 0, stream>>>(logits, b2, cmr, out);
}

// Round 15
// 156.246 us; speedup vs baseline: 1.0738x; 1.0138x over previous
//
#include <hip/hip_runtime.h>
#include <math.h>

// Problem constants
#define B64 64
#define IN_SH 10000
#define EXP_SH 53
#define HID 1500
#define NPAD1 1536          // padded N for gemm1 accumulator
#define NBC 2048
#define K2 1553
#define KS1 20              // split-K chunks gemm1 (24*20 = 480 gemm blocks)
#define KST1 16             // 16 steps of 32 => kchunk 512 (20*512 = 10240 = padded K)
#define KS2 7               // 32*7 = 224 blocks
#define KST2 8              // 8 steps of 32 => kchunk 256 (7*256 = 1792 = padded K2)
#define XSTEP 56            // Xf k-steps (1792/32), zero-padded past 1553
#define CMCH 32             // colmax row chunks
#define CMBLK 256           // colmax blocks (8 j-tiles x 32 row-chunks)
#define WLDS 640            // dwords per wave LDS buffer (32 rows * 20)

using short8  = __attribute__((ext_vector_type(8))) short;
using floatx4 = __attribute__((ext_vector_type(4))) float;
using uintx4  = __attribute__((ext_vector_type(4))) unsigned int;

__device__ __forceinline__ unsigned short f2bf(float f) {
    unsigned u = __float_as_uint(f);
    u += 0x7fffu + ((u >> 16) & 1u);   // RNE
    return (unsigned short)(u >> 16);
}

// B-fragment order (per 32-k step):
//   frag[(step*4 + sgrp)*64 + lane][j] = act[b = sgrp*16 + (lane&15)][k = step*32 + (lane>>4)*8 + j]

// Node 1: [0,320) build gosBf; [320,328) zero accumulators (hpre+logits contiguous).
__global__ __launch_bounds__(256) void prep_k(const float* __restrict__ g,
                                              unsigned short* __restrict__ gosBf,
                                              float* __restrict__ accz) {
    int bi = blockIdx.x;
    if (bi < 320) {
        int t    = bi * 256 + threadIdx.x;   // [0, 81920)
        int lane = t & 63;
        int sgrp = (t >> 6) & 3;
        int step = t >> 8;                   // [0, 320)
        int q    = lane >> 4;
        int l15  = lane & 15;
        int b    = sgrp * 16 + l15;
        int k0   = step * 32 + q * 8;
        const float* p = g + (size_t)b * IN_SH + k0;
        unsigned int o[4];
        #pragma unroll
        for (int i = 0; i < 4; i++) {
            float lo = (k0 + 2 * i     < IN_SH) ? p[2 * i]     : 0.f;
            float hi = (k0 + 2 * i + 1 < IN_SH) ? p[2 * i + 1] : 0.f;
            o[i] = (unsigned)f2bf(lo) | ((unsigned)f2bf(hi) << 16);
        }
        uintx4 v; v.x = o[0]; v.y = o[1]; v.z = o[2]; v.w = o[3];
        *(uintx4*)(gosBf + (size_t)t * 8) = v;
    } else {
        // zero 229376 floats: 8 blocks * 256 thr * 28 float4
        int t = (bi - 320) * 256 + threadIdx.x;
        floatx4 z = (floatx4){0.f, 0.f, 0.f, 0.f};
        #pragma unroll
        for (int i = 0; i < 28; i++)
            *(floatx4*)(accz + (size_t)(i * 2048 + t) * 4) = z;
    }
}

__device__ __forceinline__ void load_b4(const unsigned short* __restrict__ bf,
                                        int stg, uintx4 bv[4]) {
    #pragma unroll
    for (int s = 0; s < 4; s++)
        bv[s] = *(const uintx4*)(bf + (size_t)(stg * 4 + s) * 512);
}

// Barrier-free MFMA GEMM core (r11/r13/r14). Each wave stages its own
// 16-column W sub-tile into a wave-private LDS double buffer (intra-wave DS
// ops are in-order -> no __syncthreads in the K-loop; compiler emits
// fine-grained vmcnt/lgkmcnt). fp32 atomicAdd accumulation into accbuf[n*64+b].
template<int KSTEPS>
__device__ __forceinline__ void gemm_core(
    const float* __restrict__ W, const unsigned short* __restrict__ Bfc,
    float* __restrict__ accbuf, int N, int K, int ldw, int bx, int by, int tid,
    float* __restrict__ ldsw)   // this wave's 2*WLDS-dword region
{
    int lane = tid & 63;
    int q    = lane >> 4;
    int l15  = lane & 15;
    int n0   = bx * 64 + 16 * (tid >> 6);   // this wave's 16 columns
    int k0   = by * (KSTEPS * 32);
    bool fast = (n0 + 16 <= N) && (k0 + KSTEPS * 32 <= K);
    int kl  = lane >> 2;                    // 0..15  (staging row)
    int c4  = (lane & 3) * 4;               // staging col offset

    const unsigned short* bf = Bfc + (size_t)lane * 8;

    floatx4 acc[4];
    #pragma unroll
    for (int s = 0; s < 4; s++) acc[s] = (floatx4){0.f, 0.f, 0.f, 0.f};

    floatx4 g[2][2];   // [stage parity][row half]

    #define GLB(st, slot)                                                        \
        {                                                                        \
            int kb_ = k0 + (st) * 32;                                            \
            _Pragma("unroll")                                                    \
            for (int i_ = 0; i_ < 2; i_++) {                                     \
                int kg_ = kb_ + kl + 16 * i_;                                    \
                if (fast) {                                                      \
                    g[slot][i_] = *(const floatx4*)(W + (size_t)kg_ * ldw + n0 + c4); \
                } else {                                                         \
                    _Pragma("unroll")                                            \
                    for (int j_ = 0; j_ < 4; j_++)                               \
                        g[slot][i_][j_] = (kg_ < K && n0 + c4 + j_ < N)          \
                            ? W[(size_t)kg_ * ldw + n0 + c4 + j_] : 0.f;         \
                }                                                                \
            }                                                                    \
        }
    #define LWR(buf, slot)                                                       \
        {                                                                        \
            _Pragma("unroll")                                                    \
            for (int i_ = 0; i_ < 2; i_++)                                       \
                *(floatx4*)(ldsw + (buf) * WLDS + (kl + 16 * i_) * 20 + c4) = g[slot][i_]; \
        }

    GLB(0, 0);
    if (KSTEPS > 1) GLB(1, 1);
    LWR(0, 0);

    uintx4 bv[2][4];
    load_b4(bf, 0, bv[0]);
    if (KSTEPS > 1) load_b4(bf, 1, bv[1]);

    #pragma unroll
    for (int st = 0; st < KSTEPS; st++) {
        const int s = st & 1;                     // compile-time after unroll
        const float* lb = ldsw + s * WLDS;

        short8 af;
        #pragma unroll
        for (int j = 0; j < 8; j++)
            af[j] = (short)f2bf(lb[(q * 8 + j) * 20 + l15]);

        uintx4 bt[4];
        if (st + 2 < KSTEPS) {
            GLB(st + 2, s);
            load_b4(bf, st + 2, bt);
        }

        #pragma unroll
        for (int m = 0; m < 4; m++) {
            short8 bf8 = __builtin_bit_cast(short8, bv[s][m]);
            acc[m] = __builtin_amdgcn_mfma_f32_16x16x32_bf16(af, bf8, acc[m], 0, 0, 0);
        }

        if (st + 1 < KSTEPS) LWR(1 - s, 1 - s);
        if (st + 2 < KSTEPS) {
            #pragma unroll
            for (int m = 0; m < 4; m++) bv[s][m] = bt[m];
        }
    }
    #undef GLB
    #undef LWR

    // D lane mapping: col=lane&15 (batch within group s), row=q*4+r (n offset)
    int nrow = n0 + q * 4;
    #pragma unroll
    for (int s = 0; s < 4; s++) {
        #pragma unroll
        for (int rr = 0; rr < 4; rr++)
            atomicAdd(&accbuf[(size_t)(nrow + rr) * 64 + s * 16 + l15], acc[s][rr]);
    }
}

// Node 2: [0,256) hpo colmax FIRST (resident from t=0, streams in gemm1's BW
// slack, retires early — r6's loss came from placing these at the grid TAIL);
// [256,736) GEMM1  h_pre += gos @ W1  (N=1500, K=10000).
__global__ __launch_bounds__(256) void gemm1_k(
    const float* __restrict__ W1, const unsigned short* __restrict__ gosBf,
    float* __restrict__ hpre, const float* __restrict__ M, float* __restrict__ cm)
{
    __shared__ float lds[4 * 2 * WLDS];
    int bi = blockIdx.x;
    if (bi < CMBLK) {
        int j  = (bi & 7) * 256 + threadIdx.x;   // 0..2047
        int i0 = (bi >> 3) * 64;
        float m = 0.0f;
        #pragma unroll 16
        for (int i = i0; i < i0 + 64; i++)
            m = fmaxf(m, M[(size_t)i * NBC + j]);
        cm[(bi >> 3) * NBC + j] = m;
    } else {
        int gb = bi - CMBLK;                     // [0, 480)
        int bx = gb % 24;
        int by = gb / 24;
        gemm_core<KST1>(W1, gosBf + (size_t)by * (KST1 * 4) * 512,
                        hpre, HID, IN_SH, HID, bx, by,
                        threadIdx.x, lds + (threadIdx.x >> 6) * (2 * WLDS));
    }
}

// Node 4: GEMM2  logits += X @ W2  (N=2048, K=1553; Xf zero-padded to 1792)
__global__ __launch_bounds__(256) void gemm2_k(
    const float* __restrict__ W2, const unsigned short* __restrict__ Xf,
    float* __restrict__ logits)
{
    __shared__ float lds[4 * 2 * WLDS];
    gemm_core<KST2>(W2, Xf + (size_t)blockIdx.y * (KST2 * 4) * 512,
                    logits, NBC, K2, NBC, blockIdx.x, blockIdx.y,
                    threadIdx.x, lds + (threadIdx.x >> 6) * (2 * WLDS));
}

// Node 3: [0,56) bias + exact GELU on h_pre, concat exp_x, emit Xf (B-fragment
// order, zero-padded to 1792); [56,64) reduce cm's 32 chunks -> cmr[2048].
__global__ __launch_bounds__(256) void combine1(
    const float* __restrict__ hpre, const float* __restrict__ b1,
    const float* __restrict__ expx, unsigned short* __restrict__ Xf,
    const float* __restrict__ cm, float* __restrict__ cmr)
{
    int bi = blockIdx.x;
    if (bi < XSTEP) {
        int t    = bi * 256 + threadIdx.x;   // [0, 14336)
        int lane = t & 63;
        int sgrp = (t >> 6) & 3;
        int step = t >> 8;                    // [0, 56)
        int q    = lane >> 4;
        int l15  = lane & 15;
        int b    = sgrp * 16 + l15;
        int kb   = step * 32 + q * 8;
        unsigned int o[4];
        #pragma unroll
        for (int i = 0; i < 4; i++) {
            unsigned int lohi[2];
            #pragma unroll
            for (int h = 0; h < 2; h++) {
                int n = kb + 2 * i + h;
                float v = 0.f;
                if (n < HID) {
                    float s = hpre[(size_t)n * 64 + b] + b1[n];
                    v = 0.5f * s * (1.0f + erff(s * 0.70710678118654752f));
                } else if (n < HID + EXP_SH) {
                    v = expx[b * EXP_SH + (n - HID)];
                }
                lohi[h] = f2bf(v);
            }
            o[i] = lohi[0] | (lohi[1] << 16);
        }
        uintx4 v; v.x = o[0]; v.y = o[1]; v.z = o[2]; v.w = o[3];
        *(uintx4*)(Xf + (size_t)t * 8) = v;
    } else {
        int j = (bi - XSTEP) * 256 + threadIdx.x;   // 0..2047
        float m = 0.f;
        #pragma unroll
        for (int c = 0; c < CMCH; c++) m = fmaxf(m, cm[c * NBC + j]);
        cmr[j] = m;
    }
}

// Node 5: bias + sigmoid on logits, multiply by pre-reduced column max
__global__ __launch_bounds__(256) void final_k(
    const float* __restrict__ logits, const float* __restrict__ b2,
    const float* __restrict__ cmr, float* __restrict__ out)
{
    int idx = blockIdx.x * 256 + threadIdx.x;   // 64*2048 threads
    int b = idx & 63;
    int j = idx >> 6;
    float s = logits[(size_t)j * 64 + b] + b2[j];
    float sig = 1.0f / (1.0f + expf(-s));
    out[(size_t)b * NBC + j] = sig * cmr[j];
}

extern "C" void kernel_launch(void* const* d_in, const int* in_sizes, int n_in,
                              void* d_out, int out_size, void* d_ws, size_t ws_size,
                              hipStream_t stream) {
    const float* gos  = (const float*)d_in[0];
    const float* expx = (const float*)d_in[1];
    const float* W1   = (const float*)d_in[2];
    const float* b1   = (const float*)d_in[3];
    const float* W2   = (const float*)d_in[4];
    const float* b2   = (const float*)d_in[5];
    const float* hpo  = (const float*)d_in[6];
    float* out = (float*)d_out;

    // workspace layout (16B-aligned offsets)
    char* ws = (char*)d_ws;
    unsigned short* gosBf = (unsigned short*)ws;                   // 320*4*64*8*2 = 1,310,720
    float* hpre   = (float*)(ws + 1310720);                        // 1536*64*4    =   393,216
    float* logits = (float*)(ws + 1310720 + 393216);               // 2048*64*4    =   524,288 (contiguous with hpre)
    unsigned short* Xf = (unsigned short*)(ws + 2228224);          // 56*4*64*8*2  =   229,376
    float* cm  = (float*)(ws + 2228224 + 229376);                  // 32*2048*4    =   262,144
    float* cmr = (float*)(ws + 2228224 + 229376 + 262144);         // 2048*4       =     8,192
    // total ~2.7 MB

    // 1) build gosBf | zero accumulators (slim)
    prep_k<<<328, 256, 0, stream>>>(gos, gosBf, hpre);

    // 2) hpo colmax (first 256 blocks) + GEMM1 (atomic split-K, KS1=20)
    gemm1_k<<<CMBLK + 24 * KS1, 256, 0, stream>>>(W1, gosBf, hpre, hpo, cm);

    // 3) bias + gelu + concat exp_x -> Xf (56 steps) | reduce cm -> cmr
    combine1<<<XSTEP + 8, 256, 0, stream>>>(hpre, b1, expx, Xf, cm, cmr);

    // 4) GEMM2 (atomic split-K, KS2=7)
    gemm2_k<<<dim3(NBC / 64, KS2), 256, 0, stream>>>(W2, Xf, logits);

    // 5) bias + sigmoid + *cmr -> out
    final_k<<<(B64 * NBC) / 256, 256, 0, stream>>>(logits, b2, cmr, out);
}